// Round 1
// baseline (72.007 us; speedup 1.0000x reference)
//
#include <hip/hip_runtime.h>
#include <math.h>

#define HW     512
#define CH     16
#define PIXELS (HW * HW)          // 262144 = 2^18
#define BATCH  8
#define RED_SLICES 128            // blocks per batch in reduction

// ---------------------------------------------------------------------------
// Kernel 1: per-block partial channel sums (deterministic, no float atomics).
// Grid: BATCH * RED_SLICES blocks, 256 threads.
// Each float4 load covers channels (idx&3)*4 .. +3; with stride 256 the
// channel group per thread is fixed = threadIdx.x & 3.
// ---------------------------------------------------------------------------
__global__ __launch_bounds__(256) void reduce_partial_kernel(
        const float* __restrict__ x, float* __restrict__ partial) {
    const int b = blockIdx.x >> 7;          // / RED_SLICES
    const int s = blockIdx.x & (RED_SLICES - 1);
    const float4* xp = (const float4*)(x + (size_t)b * PIXELS * CH);
    // float4s per batch = PIXELS*CH/4 = 1048576; per block = 8192; per thread = 32
    int idx = s * 8192 + threadIdx.x;
    float4 acc = make_float4(0.f, 0.f, 0.f, 0.f);
#pragma unroll 8
    for (int k = 0; k < 32; ++k) {
        float4 v = xp[idx + k * 256];
        acc.x += v.x; acc.y += v.y; acc.z += v.z; acc.w += v.w;
    }
    // in-wave reduce across the 16 lanes sharing (lane & 3)
    for (int off = 4; off < 64; off <<= 1) {
        acc.x += __shfl_xor(acc.x, off);
        acc.y += __shfl_xor(acc.y, off);
        acc.z += __shfl_xor(acc.z, off);
        acc.w += __shfl_xor(acc.w, off);
    }
    __shared__ float swave[4][CH];
    const int wave = threadIdx.x >> 6;
    const int lane = threadIdx.x & 63;
    if (lane < 4) {
        swave[wave][lane * 4 + 0] = acc.x;
        swave[wave][lane * 4 + 1] = acc.y;
        swave[wave][lane * 4 + 2] = acc.z;
        swave[wave][lane * 4 + 3] = acc.w;
    }
    __syncthreads();
    if (threadIdx.x < CH) {
        float t = swave[0][threadIdx.x] + swave[1][threadIdx.x]
                + swave[2][threadIdx.x] + swave[3][threadIdx.x];
        partial[(size_t)blockIdx.x * CH + threadIdx.x] = t;
    }
}

// ---------------------------------------------------------------------------
// Kernel 2: finish reduction + compute per-batch rotation params.
// One block, 128 threads: thread t owns (b = t>>4, c = t&15).
// ---------------------------------------------------------------------------
__global__ void angle_kernel(const float* __restrict__ partial,
                             const float* __restrict__ w_angle,
                             const float* __restrict__ b_angle,
                             float* __restrict__ params) {
    __shared__ float mean_s[BATCH][CH];
    const int t = threadIdx.x;
    if (t < BATCH * CH) {
        const int b = t >> 4;
        const int c = t & 15;
        float sum = 0.f;
        for (int s = 0; s < RED_SLICES; ++s)
            sum += partial[(size_t)(b * RED_SLICES + s) * CH + c];
        mean_s[b][c] = sum * (1.0f / (float)PIXELS);
    }
    __syncthreads();
    if (t < BATCH) {
        float dot = 0.f;
        for (int c = 0; c < CH; ++c) dot += mean_s[t][c] * w_angle[c];
        float tn = tanhf(dot + b_angle[0]);
        const float pi = 3.14159265358979323846f;
        float ang = fminf(fmaxf(tn * pi, -pi), pi);
        float cs = cosf(ang);
        float sn = sinf(ang);
        float x_off = (511.0f - (cs * 511.0f - sn * 511.0f)) * 0.5f;
        float y_off = (511.0f - (sn * 511.0f + cs * 511.0f)) * 0.5f;
        params[t * 4 + 0] = cs;
        params[t * 4 + 1] = sn;
        params[t * 4 + 2] = x_off;
        params[t * 4 + 3] = y_off;
    }
}

// ---------------------------------------------------------------------------
// Kernel 3: bilinear rotation gather. 4 threads per output pixel, one float4
// (4 channels) each -> fully coalesced stores.
// Grid: BATCH*PIXELS*4/256 = 32768 blocks, 256 threads.
// ---------------------------------------------------------------------------
__global__ __launch_bounds__(256) void rotate_kernel(
        const float* __restrict__ x, const float* __restrict__ params,
        float* __restrict__ out) {
    const int g = blockIdx.x * 256 + threadIdx.x;
    const int q   = g & 3;          // channel quad 0..3
    const int pix = g >> 2;         // global pixel index (b*PIXELS + p)
    const int b   = pix >> 18;      // / PIXELS
    const int p   = pix & (PIXELS - 1);
    const int oy  = p >> 9;
    const int ox  = p & (HW - 1);

    const float cs = params[b * 4 + 0];
    const float sn = params[b * 4 + 1];
    const float xo = params[b * 4 + 2];
    const float yo = params[b * 4 + 3];

    const float fx = (float)ox;
    const float fy = (float)oy;
    const float ix = cs * fx - sn * fy + xo;
    const float iy = sn * fx + cs * fy + yo;
    const float x0f = floorf(ix);
    const float y0f = floorf(iy);
    const float wx = ix - x0f;
    const float wy = iy - y0f;
    const int x0 = (int)x0f;
    const int y0 = (int)y0f;

    const float4* base = (const float4*)x + ((size_t)b * PIXELS) * 4 + q;
    auto read = [&](int yy, int xx) -> float4 {
        if ((unsigned)xx < (unsigned)HW && (unsigned)yy < (unsigned)HW)
            return base[((size_t)yy * HW + xx) * 4];
        return make_float4(0.f, 0.f, 0.f, 0.f);
    };

    float4 v00 = read(y0,     x0);
    float4 v01 = read(y0,     x0 + 1);
    float4 v10 = read(y0 + 1, x0);
    float4 v11 = read(y0 + 1, x0 + 1);

    const float wx1 = 1.0f - wx;
    const float wy1 = 1.0f - wy;
    float4 r;
    r.x = (v00.x * wx1 + v01.x * wx) * wy1 + (v10.x * wx1 + v11.x * wx) * wy;
    r.y = (v00.y * wx1 + v01.y * wx) * wy1 + (v10.y * wx1 + v11.y * wx) * wy;
    r.z = (v00.z * wx1 + v01.z * wx) * wy1 + (v10.z * wx1 + v11.z * wx) * wy;
    r.w = (v00.w * wx1 + v01.w * wx) * wy1 + (v10.w * wx1 + v11.w * wx) * wy;

    ((float4*)out)[g] = r;   // float4 index g == (pix*4 + q)
}

extern "C" void kernel_launch(void* const* d_in, const int* in_sizes, int n_in,
                              void* d_out, int out_size, void* d_ws, size_t ws_size,
                              hipStream_t stream) {
    const float* x       = (const float*)d_in[0];
    const float* w_angle = (const float*)d_in[1];
    const float* b_angle = (const float*)d_in[2];
    float* out = (float*)d_out;

    float* partial = (float*)d_ws;                         // BATCH*RED_SLICES*CH = 16384 floats
    float* params  = partial + BATCH * RED_SLICES * CH;    // 32 floats

    reduce_partial_kernel<<<BATCH * RED_SLICES, 256, 0, stream>>>(x, partial);
    angle_kernel<<<1, 128, 0, stream>>>(partial, w_angle, b_angle, params);
    rotate_kernel<<<BATCH * PIXELS * 4 / 256, 256, 0, stream>>>(x, params, out);
}

// Round 3
// 67.899 us; speedup vs baseline: 1.0605x; 1.0605x over previous
//
#include <hip/hip_runtime.h>
#include <math.h>

#define HW     512
#define CH     16
#define PIXELS (HW * HW)          // 262144 = 2^18
#define BATCH  8
#define RED_SLICES 128            // blocks per batch in reduction

typedef float f32x4 __attribute__((ext_vector_type(4)));

// ---------------------------------------------------------------------------
// Kernel 1: per-block partial channel sums (deterministic, no float atomics).
// Grid: BATCH * RED_SLICES = 1024 blocks, 256 threads.
// Loads are cached normally on purpose: x should land in L3 for the rotate
// pass to re-read.
// ---------------------------------------------------------------------------
__global__ __launch_bounds__(256) void reduce_partial_kernel(
        const float* __restrict__ x, float* __restrict__ partial) {
    const int b = blockIdx.x >> 7;          // / RED_SLICES
    const int s = blockIdx.x & (RED_SLICES - 1);
    const float4* xp = (const float4*)(x + (size_t)b * PIXELS * CH);
    // float4s per batch = 1048576; per block = 8192; per thread = 32
    int idx = s * 8192 + threadIdx.x;
    float4 acc = make_float4(0.f, 0.f, 0.f, 0.f);
#pragma unroll 8
    for (int k = 0; k < 32; ++k) {
        float4 v = xp[idx + k * 256];
        acc.x += v.x; acc.y += v.y; acc.z += v.z; acc.w += v.w;
    }
    // reduce across the 16 lanes sharing (lane & 3): channel quad is lane&3
    for (int off = 4; off < 64; off <<= 1) {
        acc.x += __shfl_xor(acc.x, off);
        acc.y += __shfl_xor(acc.y, off);
        acc.z += __shfl_xor(acc.z, off);
        acc.w += __shfl_xor(acc.w, off);
    }
    __shared__ float swave[4][CH];
    const int wave = threadIdx.x >> 6;
    const int lane = threadIdx.x & 63;
    if (lane < 4) {
        swave[wave][lane * 4 + 0] = acc.x;
        swave[wave][lane * 4 + 1] = acc.y;
        swave[wave][lane * 4 + 2] = acc.z;
        swave[wave][lane * 4 + 3] = acc.w;
    }
    __syncthreads();
    if (threadIdx.x < CH) {
        float t = swave[0][threadIdx.x] + swave[1][threadIdx.x]
                + swave[2][threadIdx.x] + swave[3][threadIdx.x];
        partial[(size_t)blockIdx.x * CH + threadIdx.x] = t;
    }
}

// ---------------------------------------------------------------------------
// Kernel 2: finish reduction + per-batch rotation params (double internally).
// One block, 128 threads: thread t owns (b = t>>4, c = t&15) for the sum.
// ---------------------------------------------------------------------------
__global__ void angle_kernel(const float* __restrict__ partial,
                             const float* __restrict__ w_angle,
                             const float* __restrict__ b_angle,
                             float* __restrict__ params) {
    __shared__ double mean_s[BATCH][CH];
    const int t = threadIdx.x;
    if (t < BATCH * CH) {
        const int b = t >> 4;
        const int c = t & 15;
        double sum = 0.0;
        for (int s = 0; s < RED_SLICES; ++s)
            sum += (double)partial[(size_t)(b * RED_SLICES + s) * CH + c];
        mean_s[b][c] = sum * (1.0 / (double)PIXELS);
    }
    __syncthreads();
    if (t < BATCH) {
        double dot = 0.0;
        for (int c = 0; c < CH; ++c) dot += mean_s[t][c] * (double)w_angle[c];
        double tn = tanh(dot + (double)b_angle[0]);
        const double pi = 3.14159265358979323846;
        double ang = fmin(fmax(tn * pi, -pi), pi);
        double cs = cos(ang);
        double sn = sin(ang);
        double x_off = (511.0 - (cs * 511.0 - sn * 511.0)) * 0.5;
        double y_off = (511.0 - (sn * 511.0 + cs * 511.0)) * 0.5;
        params[t * 4 + 0] = (float)cs;
        params[t * 4 + 1] = (float)sn;
        params[t * 4 + 2] = (float)x_off;
        params[t * 4 + 3] = (float)y_off;
    }
}

// ---------------------------------------------------------------------------
// Kernel 3: bilinear rotation gather. 4 threads per output pixel, one float4
// (4 channels) each. Nontemporal stores keep x resident in L2/L3.
// XCD swizzle: 32768 blocks = 8 images x 4096 -> each XCD owns one image, so
// bilinear row-overlap re-reads hit that XCD's private L2.
// ---------------------------------------------------------------------------
__global__ __launch_bounds__(256) void rotate_kernel(
        const float* __restrict__ x, const float* __restrict__ params,
        float* __restrict__ out) {
    int bid = blockIdx.x;
    bid = ((bid & 7) << 12) | (bid >> 3);   // nwg = 32768, nwg/8 = 4096
    const int g = bid * 256 + threadIdx.x;
    const int q   = g & 3;          // channel quad 0..3
    const int pix = g >> 2;         // global pixel index (b*PIXELS + p)
    const int b   = pix >> 18;      // / PIXELS
    const int p   = pix & (PIXELS - 1);
    const int oy  = p >> 9;
    const int ox  = p & (HW - 1);

    const float cs = params[b * 4 + 0];
    const float sn = params[b * 4 + 1];
    const float xo = params[b * 4 + 2];
    const float yo = params[b * 4 + 3];

    const float fx = (float)ox;
    const float fy = (float)oy;
    const float ix = cs * fx - sn * fy + xo;
    const float iy = sn * fx + cs * fy + yo;
    const float x0f = floorf(ix);
    const float y0f = floorf(iy);
    const float wx = ix - x0f;
    const float wy = iy - y0f;
    const int x0 = (int)x0f;
    const int y0 = (int)y0f;

    const float4* base = (const float4*)x + ((size_t)b * PIXELS) * 4 + q;

    float4 v00, v01, v10, v11;
    if (x0 >= 0 && y0 >= 0 && x0 < HW - 1 && y0 < HW - 1) {
        // interior: all four taps valid (the overwhelmingly common case)
        const float4* row0 = base + (size_t)y0 * (HW * 4);
        v00 = row0[(size_t)x0 * 4];
        v01 = row0[(size_t)(x0 + 1) * 4];
        const float4* row1 = row0 + HW * 4;
        v10 = row1[(size_t)x0 * 4];
        v11 = row1[(size_t)(x0 + 1) * 4];
    } else {
        auto read = [&](int yy, int xx) -> float4 {
            if ((unsigned)xx < (unsigned)HW && (unsigned)yy < (unsigned)HW)
                return base[((size_t)yy * HW + xx) * 4];
            return make_float4(0.f, 0.f, 0.f, 0.f);
        };
        v00 = read(y0,     x0);
        v01 = read(y0,     x0 + 1);
        v10 = read(y0 + 1, x0);
        v11 = read(y0 + 1, x0 + 1);
    }

    const float wx1 = 1.0f - wx;
    const float wy1 = 1.0f - wy;
    f32x4 r;
    r.x = (v00.x * wx1 + v01.x * wx) * wy1 + (v10.x * wx1 + v11.x * wx) * wy;
    r.y = (v00.y * wx1 + v01.y * wx) * wy1 + (v10.y * wx1 + v11.y * wx) * wy;
    r.z = (v00.z * wx1 + v01.z * wx) * wy1 + (v10.z * wx1 + v11.z * wx) * wy;
    r.w = (v00.w * wx1 + v01.w * wx) * wy1 + (v10.w * wx1 + v11.w * wx) * wy;

    __builtin_nontemporal_store(r, (f32x4*)out + g);
}

extern "C" void kernel_launch(void* const* d_in, const int* in_sizes, int n_in,
                              void* d_out, int out_size, void* d_ws, size_t ws_size,
                              hipStream_t stream) {
    const float* x       = (const float*)d_in[0];
    const float* w_angle = (const float*)d_in[1];
    const float* b_angle = (const float*)d_in[2];
    float* out = (float*)d_out;

    float* partial = (float*)d_ws;                         // 16384 floats
    float* params  = partial + BATCH * RED_SLICES * CH;    // 32 floats

    reduce_partial_kernel<<<BATCH * RED_SLICES, 256, 0, stream>>>(x, partial);
    angle_kernel<<<1, 128, 0, stream>>>(partial, w_angle, b_angle, params);
    rotate_kernel<<<BATCH * PIXELS * 4 / 256, 256, 0, stream>>>(x, params, out);
}